// Round 9
// baseline (428.061 us; speedup 1.0000x reference)
//
#include <hip/hip_runtime.h>
#include <hip/hip_fp16.h>

#define D 64
#define NBMAX 512      // max buckets (nodes/256, N<=131072)
#define BCAP 5120      // per-bucket capacity; mean E/nb=4092, sigma~64 -> 16-sigma margin

static __device__ __forceinline__ float bcast_lane(float x, int k) {
    return __int_as_float(__builtin_amdgcn_readlane(__float_as_int(x), k));
}

__global__ void zero_ints(int* __restrict__ p, int n) {
    int i = blockIdx.x * blockDim.x + threadIdx.x;
    if (i < n) p[i] = 0;
}

// x (fp32) -> xh (fp16), pre-scaled by dis[row]: s = dis[n]*x[n]
__global__ void prescale_x(const float* __restrict__ x, const float* __restrict__ dis,
                           __half* __restrict__ out, int n2) {
    int i = blockIdx.x * blockDim.x + threadIdx.x;
    if (i < n2) {
        int n = i >> 5;                 // 32 half2 per row
        float d = dis[n];
        float2 v = ((const float2*)x)[i];
        ((__half2*)out)[i] = __floats2half2_rn(v.x * d, v.y * d);
    }
}

// Bin edges into buckets of 256 consecutive dst nodes. Entry packed to 4B:
// (src << 8) | (dst & 255)   (src < 2^24).
__global__ __launch_bounds__(256) void bucket_scatter(const int* __restrict__ src,
                                                      const int* __restrict__ dst, int E,
                                                      int nb, int* __restrict__ gcursor,
                                                      unsigned* __restrict__ bpair) {
    __shared__ int lhist[NBMAX];
    __shared__ int lbase[NBMAX];
    int t = threadIdx.x;
    for (int i = t; i < nb; i += 256) lhist[i] = 0;
    __syncthreads();
    int e0 = blockIdx.x * 4096, e1 = min(e0 + 4096, E);
    for (int e = e0 + t; e < e1; e += 256) atomicAdd(&lhist[dst[e] >> 8], 1);
    __syncthreads();
    for (int i = t; i < nb; i += 256) {
        int c = lhist[i];
        lbase[i] = c ? atomicAdd(&gcursor[i], c) : 0;
        lhist[i] = 0;
    }
    __syncthreads();
    for (int e = e0 + t; e < e1; e += 256) {
        int d = dst[e];
        int b = d >> 8;
        int r = lbase[b] + atomicAdd(&lhist[b], 1);
        if (r < BCAP)
            bpair[(long)b * BCAP + r] = ((unsigned)src[e] << 8) | (unsigned)(d & 255);
    }
}

// Exclusive scan of nb (<512) bucket counts -> gbase, total at gbase[nb].
__global__ void scan_buckets(const int* __restrict__ gcursor, int B, int* __restrict__ gbase) {
    __shared__ int s[512];
    int t = threadIdx.x;
    s[t] = (t < B) ? gcursor[t] : 0;
    __syncthreads();
    for (int off = 1; off < 512; off <<= 1) {
        int v = (t >= off) ? s[t - off] : 0;
        __syncthreads();
        s[t] += v;
        __syncthreads();
    }
    if (t < B) gbase[t] = (t == 0) ? 0 : s[t - 1];
    if (t == 0) gbase[B] = s[511];
}

// One block per bucket: local histogram + scan in LDS, emit row_ptr/dis/adj_src.
__global__ __launch_bounds__(256) void bucket_build(const unsigned* __restrict__ bpair,
                                                    int nb, int N,
                                                    const int* __restrict__ gcursor,
                                                    const int* __restrict__ gbase,
                                                    int* __restrict__ row_ptr,
                                                    float* __restrict__ dis,
                                                    int* __restrict__ adj_src) {
    __shared__ int hist[256];
    __shared__ int cur[256];
    __shared__ int wsum[4];
    int b = blockIdx.x, t = threadIdx.x;
    int cnt = gcursor[b];
    if (cnt > BCAP) cnt = BCAP;
    int ebase = gbase[b];
    const unsigned* bp = bpair + (long)b * BCAP;

    hist[t] = 0;
    __syncthreads();
    for (int i = t; i < cnt; i += 256) atomicAdd(&hist[bp[i] & 255u], 1);
    __syncthreads();
    int val = hist[t];
    int lane = t & 63, wv = t >> 6;
    int v = val;
#pragma unroll
    for (int off = 1; off < 64; off <<= 1) {
        int u = __shfl_up(v, off, 64);
        if (lane >= off) v += u;
    }
    if (lane == 63) wsum[wv] = v;
    __syncthreads();
    int wo = 0;
#pragma unroll
    for (int w = 0; w < 4; w++)
        if (w < wv) wo += wsum[w];
    int excl = wo + v - val;
    int node = (b << 8) + t;
    if (node < N) {
        row_ptr[node] = ebase + excl;
        dis[node] = rsqrtf((float)(val + 1));  // +1 self-loop
    }
    cur[t] = ebase + excl;
    __syncthreads();
    for (int i = t; i < cnt; i += 256) {
        unsigned p = bp[i];
        int pos = atomicAdd(&cur[p & 255u], 1);
        adj_src[pos] = (int)(p >> 8);
    }
    if (b == 0 && t == 0) row_ptr[N] = gbase[nb];
}

// Fused GCN layer on pre-scaled storage s[n] = dis[n]*h[n]:
//   y[n] = dis[n] * ( sum_a s[a] + s[n] );  o = relu(y @ W + b); store o (*dis if scale_out)
// Wide gather: lane L = (edge-slot g=L>>3, chunk c=L&7). Per 8 edges: one
// broadcast adj load (no shfl on critical path) + one dwordx4 load fetching 16B
// chunks of 8 different rows. fp32 accumulate (8 slots/lane); 3x shfl_xor
// group-reduction per node. 2 interleaved nodes; masked tails; self-loop as
// masked pseudo-edge in group 0. Shared-W readlane epilogue.
__global__ __launch_bounds__(256) void fused_layer(const __half* __restrict__ in,
                                                   const int* __restrict__ row_ptr,
                                                   const int* __restrict__ adj_src,
                                                   const float* __restrict__ dis,
                                                   const float* __restrict__ Wg,
                                                   const float* __restrict__ bias,
                                                   __half* __restrict__ out, int N,
                                                   int total_waves, int scale_out) {
    __shared__ float Wlds[D * D];
#pragma unroll
    for (int r = 0; r < 16; r++) Wlds[r * 256 + threadIdx.x] = Wg[r * 256 + threadIdx.x];
    int lane = threadIdx.x & 63;
    int gs = lane >> 3;      // edge slot 0..7
    int cs = lane & 7;       // 16B chunk within row
    float bl = bias[lane];
    __syncthreads();

    const int4* in4 = (const int4*)in;       // row n = 8 int4

    int wave = (blockIdx.x * blockDim.x + threadIdx.x) >> 6;
    for (int n0 = wave; n0 < N; n0 += 2 * total_waves) {
        int n1 = n0 + total_waves;
        bool has1 = (n1 < N);
        float dn0 = dis[n0];
        int e0 = row_ptr[n0], E0 = row_ptr[n0 + 1];
        float dn1 = 0.f;
        int e1 = 0, E1 = 0;
        if (has1) { dn1 = dis[n1]; e1 = row_ptr[n1]; E1 = row_ptr[n1 + 1]; }

        float a0[8], a1[8];
#pragma unroll
        for (int r = 0; r < 8; r++) { a0[r] = 0.f; a1[r] = 0.f; }

        // self-loop pseudo-edge: only group 0 contributes
        {
            int4 sv = in4[(long)n0 * 8 + cs];
            if (gs != 0) sv = make_int4(0, 0, 0, 0);
#pragma unroll
            for (int q = 0; q < 4; q++) {
                int wq = (&sv.x)[q];
                __half2 hh; *(int*)&hh = wq;
                float2 f = __half22float2(hh);
                a0[2 * q] += f.x; a0[2 * q + 1] += f.y;
            }
            if (has1) {
                int4 sw = in4[(long)n1 * 8 + cs];
                if (gs != 0) sw = make_int4(0, 0, 0, 0);
#pragma unroll
                for (int q = 0; q < 4; q++) {
                    int wq = (&sw.x)[q];
                    __half2 hh; *(int*)&hh = wq;
                    float2 f = __half22float2(hh);
                    a1[2 * q] += f.x; a1[2 * q + 1] += f.y;
                }
            }
        }

        // main loop: per live node, 1 adj broadcast load + 1 dwordx4 row-gather per 8 edges
        while (e0 < E0 || e1 < E1) {
            bool d0 = (e0 < E0), d1 = (e1 < E1);
            int4 r0, r1;
            bool ok0 = false, ok1 = false;
            if (d0) {
                int idx = e0 + gs;
                ok0 = idx < E0;
                int aa = adj_src[ok0 ? idx : E0 - 1];
                r0 = in4[(long)aa * 8 + cs];
            }
            if (d1) {
                int idx = e1 + gs;
                ok1 = idx < E1;
                int aa = adj_src[ok1 ? idx : E1 - 1];
                r1 = in4[(long)aa * 8 + cs];
            }
            if (d0) {
                if (!ok0) r0 = make_int4(0, 0, 0, 0);
#pragma unroll
                for (int q = 0; q < 4; q++) {
                    int wq = (&r0.x)[q];
                    __half2 hh; *(int*)&hh = wq;
                    float2 f = __half22float2(hh);
                    a0[2 * q] += f.x; a0[2 * q + 1] += f.y;
                }
                e0 += 8;
            }
            if (d1) {
                if (!ok1) r1 = make_int4(0, 0, 0, 0);
#pragma unroll
                for (int q = 0; q < 4; q++) {
                    int wq = (&r1.x)[q];
                    __half2 hh; *(int*)&hh = wq;
                    float2 f = __half22float2(hh);
                    a1[2 * q] += f.x; a1[2 * q + 1] += f.y;
                }
                e1 += 8;
            }
        }

        // reduce over the 8 edge-groups (lanes differing in bits 3..5), scale by dn
#pragma unroll
        for (int r = 0; r < 8; r++) {
            a0[r] += __shfl_xor(a0[r], 8, 64);
            a0[r] += __shfl_xor(a0[r], 16, 64);
            a0[r] += __shfl_xor(a0[r], 32, 64);
            a0[r] *= dn0;
            if (has1) {
                a1[r] += __shfl_xor(a1[r], 8, 64);
                a1[r] += __shfl_xor(a1[r], 16, 64);
                a1[r] += __shfl_xor(a1[r], 32, 64);
                a1[r] *= dn1;
            }
        }

        // epilogue: y[8c+r] lives in lane c as a?[r]; one Wlds read feeds both nodes
        float o0 = bl, o1 = bl;
#pragma unroll
        for (int c = 0; c < 8; c++) {
#pragma unroll
            for (int r = 0; r < 8; r++) {
                float w = Wlds[(8 * c + r) * D + lane];
                o0 = fmaf(bcast_lane(a0[r], c), w, o0);
                o1 = fmaf(bcast_lane(a1[r], c), w, o1);
            }
        }
        float r0v = fmaxf(o0, 0.f);
        if (scale_out) r0v *= dn0;
        out[(long)n0 * D + lane] = __float2half(r0v);
        if (has1) {
            float r1v = fmaxf(o1, 0.f);
            if (scale_out) r1v *= dn1;
            out[(long)n1 * D + lane] = __float2half(r1v);
        }
    }
}

// Pool phase 1: grid-chunked over sorted nodes; per-wave run accumulation,
// one atomicAdd per (graph-run, lane) per wave.
__global__ __launch_bounds__(256) void pool_partial(const __half* __restrict__ h,
                                                    const int* __restrict__ batch, int N,
                                                    int chunk, float* __restrict__ pooled) {
    int lane = threadIdx.x & 63;
    int wv = threadIdx.x >> 6;
    int c0 = blockIdx.x * chunk;
    int c1 = min(c0 + chunk, N);
    int g_cur = -1;
    float acc = 0.f;
    for (int n = c0 + wv; n < c1; n += 4) {
        int g = batch[n];
        if (g != g_cur) {
            if (g_cur >= 0) atomicAdd(&pooled[g_cur * D + lane], acc);
            g_cur = g;
            acc = 0.f;
        }
        acc += __half2float(h[n * D + lane]);
    }
    if (g_cur >= 0) atomicAdd(&pooled[g_cur * D + lane], acc);
}

// Pool phase 2: one wave per graph, dot with lin_w.
__global__ void pool_linear(const float* __restrict__ pooled,
                            const float* __restrict__ lin_w,
                            const float* __restrict__ lin_b,
                            float* __restrict__ out, int G) {
    int lane = threadIdx.x & 63;
    int g = blockIdx.x * (blockDim.x >> 6) + (threadIdx.x >> 6);
    if (g >= G) return;
    float t = pooled[g * D + lane] * lin_w[lane];
#pragma unroll
    for (int off = 32; off >= 1; off >>= 1) t += __shfl_down(t, off, 64);
    if (lane == 0) out[g] = t + lin_b[0];
}

extern "C" void kernel_launch(void* const* d_in, const int* in_sizes, int n_in,
                              void* d_out, int out_size, void* d_ws, size_t ws_size,
                              hipStream_t stream) {
    const float* x      = (const float*)d_in[0];
    const int*   edges  = (const int*)d_in[1];
    const int*   batch  = (const int*)d_in[2];
    const float* W1     = (const float*)d_in[3];
    const float* b1     = (const float*)d_in[4];
    const float* W2     = (const float*)d_in[5];
    const float* b2     = (const float*)d_in[6];
    const float* W3     = (const float*)d_in[7];
    const float* b3     = (const float*)d_in[8];
    const float* lin_w  = (const float*)d_in[9];
    const float* lin_b  = (const float*)d_in[10];
    float* out = (float*)d_out;

    const int N = in_sizes[2];        // 100000
    const int E = in_sizes[1] / 2;    // 1600000
    const int G = out_size;           // 64 graphs
    const int nb = (N + 255) >> 8;    // 391 buckets of 256 nodes

    const int* e_src = edges;         // edge_index[0]
    const int* e_dst = edges + E;     // edge_index[1]

    // workspace layout (4B-element offsets, 64-elem aligned)
    auto al = [](long v) { return (v + 63) & ~63L; };
    long o_gcur   = 0;                       // NBMAX ints
    long o_pooled = al(o_gcur + NBMAX);      // G*D floats
    long o_gbase  = al(o_pooled + (long)G * D);
    long o_rowptr = al(o_gbase + nb + 1);
    long o_dis    = al(o_rowptr + N + 1);
    long o_adjs   = al(o_dis + N);
    long o_xh     = al(o_adjs + E);              // N*D halves
    long o_hA     = al(o_xh + (long)N * D / 2);  // aliases bpair (8MB < 25.6MB slot)
    long o_hB     = o_hA + (long)N * D;          // fp32-sized slots used as half buffers

    int*    gcursor = (int*)d_ws + o_gcur;
    float*  pooled  = (float*)d_ws + o_pooled;
    int*    gbase   = (int*)d_ws + o_gbase;
    int*    row_ptr = (int*)d_ws + o_rowptr;
    float*  dis     = (float*)d_ws + o_dis;
    int*    adj_src = (int*)d_ws + o_adjs;
    __half* xh      = (__half*)((float*)d_ws + o_xh);
    __half* hA      = (__half*)((float*)d_ws + o_hA);
    __half* hB      = (__half*)((float*)d_ws + o_hB);
    // bpair (nb*BCAP uints = 8 MB) aliases hA slot: dead before layer 2 writes hA.
    unsigned* bpair = (unsigned*)hA;

    // zero gcursor + pooled (contiguous)
    int nz = (int)(o_pooled + (long)G * D);
    zero_ints<<<(nz + 255) / 256, 256, 0, stream>>>((int*)d_ws, nz);

    // CSR build first (produces dis), then pre-scaled fp16 convert of x
    bucket_scatter<<<(E + 4095) / 4096, 256, 0, stream>>>(e_src, e_dst, E, nb, gcursor, bpair);
    scan_buckets<<<1, 512, 0, stream>>>(gcursor, nb, gbase);
    bucket_build<<<nb, 256, 0, stream>>>(bpair, nb, N, gcursor, gbase, row_ptr, dis, adj_src);

    int n2 = N * D / 2;
    prescale_x<<<(n2 + 255) / 256, 256, 0, stream>>>(x, dis, xh, n2);

    // fused GCN layers: xh -> hB -> hA -> hB
    // layers 1,2 store dis-pre-scaled output; layer 3 stores plain relu for pooling
    const int fl_blocks = 4096;
    const int total_waves = fl_blocks * 4;
    fused_layer<<<fl_blocks, 256, 0, stream>>>(xh, row_ptr, adj_src, dis, W1, b1, hB, N, total_waves, 1);
    fused_layer<<<fl_blocks, 256, 0, stream>>>(hB, row_ptr, adj_src, dis, W2, b2, hA, N, total_waves, 1);
    fused_layer<<<fl_blocks, 256, 0, stream>>>(hA, row_ptr, adj_src, dis, W3, b3, hB, N, total_waves, 0);

    // pool + final linear
    const int pool_blocks = 512;
    const int chunk = (N + pool_blocks - 1) / pool_blocks;
    pool_partial<<<pool_blocks, 256, 0, stream>>>(hB, batch, N, chunk, pooled);
    pool_linear<<<(G + 3) / 4, 256, 0, stream>>>(pooled, lin_w, lin_b, out, G);
}

// Round 10
// 407.887 us; speedup vs baseline: 1.0495x; 1.0495x over previous
//
#include <hip/hip_runtime.h>
#include <hip/hip_fp16.h>

#define D 64
#define NBMAX 512      // max buckets (nodes/256, N<=131072)
#define BCAP 5120      // per-bucket capacity
#define TILE 64        // nodes per block in tile_layer
#define AST 68         // LDS acc row stride in floats (breaks pow-2 banks, 16B-aligned)

typedef __attribute__((ext_vector_type(8))) short short8;
typedef __attribute__((ext_vector_type(4))) float float4v;

static __device__ __forceinline__ unsigned short f2bf(float x) {
    unsigned u = __float_as_uint(x);
    u += 0x7FFFu + ((u >> 16) & 1);   // RNE
    return (unsigned short)(u >> 16);
}

__global__ void zero_ints(int* __restrict__ p, int n) {
    int i = blockIdx.x * blockDim.x + threadIdx.x;
    if (i < n) p[i] = 0;
}

// x (fp32) -> xh (fp16), pre-scaled by dis[row]: s = dis[n]*x[n]
__global__ void prescale_x(const float* __restrict__ x, const float* __restrict__ dis,
                           __half* __restrict__ out, int n2) {
    int i = blockIdx.x * blockDim.x + threadIdx.x;
    if (i < n2) {
        int n = i >> 5;                 // 32 half2 per row
        float d = dis[n];
        float2 v = ((const float2*)x)[i];
        ((__half2*)out)[i] = __floats2half2_rn(v.x * d, v.y * d);
    }
}

// Bin edges into buckets of 256 consecutive dst nodes. Entry packed to 4B:
// (src << 8) | (dst & 255)   (src < 2^24).
__global__ __launch_bounds__(256) void bucket_scatter(const int* __restrict__ src,
                                                      const int* __restrict__ dst, int E,
                                                      int nb, int* __restrict__ gcursor,
                                                      unsigned* __restrict__ bpair) {
    __shared__ int lhist[NBMAX];
    __shared__ int lbase[NBMAX];
    int t = threadIdx.x;
    for (int i = t; i < nb; i += 256) lhist[i] = 0;
    __syncthreads();
    int e0 = blockIdx.x * 4096, e1 = min(e0 + 4096, E);
    for (int e = e0 + t; e < e1; e += 256) atomicAdd(&lhist[dst[e] >> 8], 1);
    __syncthreads();
    for (int i = t; i < nb; i += 256) {
        int c = lhist[i];
        lbase[i] = c ? atomicAdd(&gcursor[i], c) : 0;
        lhist[i] = 0;
    }
    __syncthreads();
    for (int e = e0 + t; e < e1; e += 256) {
        int d = dst[e];
        int b = d >> 8;
        int r = lbase[b] + atomicAdd(&lhist[b], 1);
        if (r < BCAP)
            bpair[(long)b * BCAP + r] = ((unsigned)src[e] << 8) | (unsigned)(d & 255);
    }
}

// Exclusive scan of nb (<512) bucket counts -> gbase, total at gbase[nb].
__global__ void scan_buckets(const int* __restrict__ gcursor, int B, int* __restrict__ gbase) {
    __shared__ int s[512];
    int t = threadIdx.x;
    s[t] = (t < B) ? gcursor[t] : 0;
    __syncthreads();
    for (int off = 1; off < 512; off <<= 1) {
        int v = (t >= off) ? s[t - off] : 0;
        __syncthreads();
        s[t] += v;
        __syncthreads();
    }
    if (t < B) gbase[t] = (t == 0) ? 0 : s[t - 1];
    if (t == 0) gbase[B] = s[511];
}

// One block per bucket: local histogram + scan in LDS, emit row_ptr/dis and
// adj entries packed as (src << 6) | (dst & 63)  (tile-local dst, TILE=64).
__global__ __launch_bounds__(256) void bucket_build(const unsigned* __restrict__ bpair,
                                                    int nb, int N,
                                                    const int* __restrict__ gcursor,
                                                    const int* __restrict__ gbase,
                                                    int* __restrict__ row_ptr,
                                                    float* __restrict__ dis,
                                                    int* __restrict__ adj) {
    __shared__ int hist[256];
    __shared__ int cur[256];
    __shared__ int wsum[4];
    int b = blockIdx.x, t = threadIdx.x;
    int cnt = gcursor[b];
    if (cnt > BCAP) cnt = BCAP;
    int ebase = gbase[b];
    const unsigned* bp = bpair + (long)b * BCAP;

    hist[t] = 0;
    __syncthreads();
    for (int i = t; i < cnt; i += 256) atomicAdd(&hist[bp[i] & 255u], 1);
    __syncthreads();
    int val = hist[t];
    int lane = t & 63, wv = t >> 6;
    int v = val;
#pragma unroll
    for (int off = 1; off < 64; off <<= 1) {
        int u = __shfl_up(v, off, 64);
        if (lane >= off) v += u;
    }
    if (lane == 63) wsum[wv] = v;
    __syncthreads();
    int wo = 0;
#pragma unroll
    for (int w = 0; w < 4; w++)
        if (w < wv) wo += wsum[w];
    int excl = wo + v - val;
    int node = (b << 8) + t;
    if (node < N) {
        row_ptr[node] = ebase + excl;
        dis[node] = rsqrtf((float)(val + 1));  // +1 self-loop
    }
    cur[t] = ebase + excl;
    __syncthreads();
    for (int i = t; i < cnt; i += 256) {
        unsigned p = bp[i];
        unsigned dl = p & 255u;
        int pos = atomicAdd(&cur[dl], 1);
        adj[pos] = (int)((p >> 8) << 6) | (int)(dl & 63u);
    }
    if (b == 0 && t == 0) row_ptr[N] = gbase[nb];
}

// Tile GCN layer on pre-scaled storage s[n] = dis[n]*h[n]:
//   y[n] = dis[n] * ( sum_a s[a] + s[n] );  o = relu(y @ W + b); store (*dis if scale_out)
// Block = 64-node tile. Phase 1: edge-parallel sweep — each wave takes a
// contiguous quarter of the tile's CSR edge range, split into 8 group-streams
// (lane = (group g, chunk c)). Per iteration: 1 adj dword (packed src|dst_local)
// + 1 dwordx4 fetching 16B chunks of 8 rows. Run-accumulate per lane (CSR runs
// share dst), flush to LDS fp32 acc via atomicAdd on node change. No shfl,
// no loop-carried deps. Phase 2: per-wave MFMA (16 nodes x 64) @ W.
__global__ __launch_bounds__(256) void tile_layer(const __half* __restrict__ in,
                                                  const int* __restrict__ row_ptr,
                                                  const int* __restrict__ adj,
                                                  const float* __restrict__ dis,
                                                  const float* __restrict__ Wg,
                                                  const float* __restrict__ bias,
                                                  __half* __restrict__ out,
                                                  int N, int scale_out) {
    __shared__ float acc[TILE * AST];   // 17408 B

    int t = threadIdx.x;
    int lane = t & 63;
    int w = t >> 6;
    int gs = lane >> 3, cs = lane & 7;
    int col = lane & 15, quad = lane >> 4;

    int t0 = blockIdx.x * TILE;
    int nend = min(t0 + TILE, N);

    // init: acc row n = s[n] (self-loop term), zeros for padding rows
#pragma unroll
    for (int i = 0; i < 16; i++) {
        int nl = w * 16 + i;
        int n = t0 + nl;
        float v = (n < nend) ? __half2float(in[(long)n * D + lane]) : 0.f;
        acc[nl * AST + lane] = v;
    }
    __syncthreads();

    // ---- edge sweep ----
    int eb = row_ptr[t0];
    int ee = row_ptr[nend];
    int etot = ee - eb;
    int per = (etot + 3) >> 2;
    int a0 = eb + w * per;
    int b0 = min(a0 + per, ee);
    int wlen = b0 - a0;
    const int4* in4 = (const int4*)in;

    if (wlen > 0) {
        int glen = (wlen + 7) >> 3;
        int gstart = a0 + gs * glen;
        int gend = min(gstart + glen, b0);
        int cur_nl = -1;
        float racc[8];
#pragma unroll
        for (int q = 0; q < 8; q++) racc[q] = 0.f;

#pragma unroll 2
        for (int i = 0; i < glen; i++) {
            int idx = gstart + i;
            bool ok = idx < gend;
            int cidx = ok ? idx : (b0 - 1);
            int pk = adj[cidx];
            int src = pk >> 6;
            int nl = ok ? (pk & 63) : cur_nl;
            if (nl != cur_nl) {
                if (cur_nl >= 0) {
                    float* bp = &acc[cur_nl * AST + cs * 8];
#pragma unroll
                    for (int q = 0; q < 8; q++) atomicAdd(bp + q, racc[q]);
                }
#pragma unroll
                for (int q = 0; q < 8; q++) racc[q] = 0.f;
                cur_nl = nl;
            }
            int4 rr = in4[(long)src * 8 + cs];
            if (ok) {
                float2 f0 = __half22float2(*(__half2*)&rr.x);
                float2 f1 = __half22float2(*(__half2*)&rr.y);
                float2 f2 = __half22float2(*(__half2*)&rr.z);
                float2 f3 = __half22float2(*(__half2*)&rr.w);
                racc[0] += f0.x; racc[1] += f0.y;
                racc[2] += f1.x; racc[3] += f1.y;
                racc[4] += f2.x; racc[5] += f2.y;
                racc[6] += f3.x; racc[7] += f3.y;
            }
        }
        if (cur_nl >= 0) {
            float* bp = &acc[cur_nl * AST + cs * 8];
#pragma unroll
            for (int q = 0; q < 8; q++) atomicAdd(bp + q, racc[q]);
        }
    }
    __syncthreads();

    // ---- MFMA epilogue: per wave, rows w*16 .. w*16+15 ----
    // B frags (W bf16): B[k=32s+quad*8+j][d=16c+col]  (R7-verified mapping)
    short8 Bf[2][4];
#pragma unroll
    for (int s = 0; s < 2; s++)
#pragma unroll
        for (int c = 0; c < 4; c++) {
            short8 f;
#pragma unroll
            for (int j = 0; j < 8; j++)
                f[j] = (short)f2bf(Wg[(32 * s + quad * 8 + j) * D + 16 * c + col]);
            Bf[s][c] = f;
        }
    float bias_c[4];
#pragma unroll
    for (int c = 0; c < 4; c++) bias_c[c] = bias[16 * c + col];

    // A frags: row m = col, k = 32s + quad*8 + j; scale row by dis (y = dn*acc)
    int arow = w * 16 + col;
    int anode = t0 + arow;
    float dA = (anode < N) ? dis[anode] : 0.f;
    short8 Af[2];
#pragma unroll
    for (int s = 0; s < 2; s++) {
        const float* ap = &acc[arow * AST + 32 * s + quad * 8];
        float4v p0 = *(const float4v*)ap;
        float4v p1 = *(const float4v*)(ap + 4);
        short8 f;
#pragma unroll
        for (int j = 0; j < 4; j++) {
            f[j] = (short)f2bf(p0[j] * dA);
            f[4 + j] = (short)f2bf(p1[j] * dA);
        }
        Af[s] = f;
    }

    float4v accv[4];
#pragma unroll
    for (int c = 0; c < 4; c++) {
        float4v z = {0.f, 0.f, 0.f, 0.f};
        accv[c] = __builtin_amdgcn_mfma_f32_16x16x32_bf16(Af[0], Bf[0][c], z, 0, 0, 0);
        accv[c] = __builtin_amdgcn_mfma_f32_16x16x32_bf16(Af[1], Bf[1][c], accv[c], 0, 0, 0);
    }

    // C layout: col = lane&15 (dim 16c+col), row = quad*4 + r (node)
#pragma unroll
    for (int r = 0; r < 4; r++) {
        int node = t0 + w * 16 + quad * 4 + r;
        if (node < N) {
            float dn = scale_out ? dis[node] : 1.f;
#pragma unroll
            for (int c = 0; c < 4; c++) {
                float vv = fmaxf(accv[c][r] + bias_c[c], 0.f) * dn;
                out[(long)node * D + 16 * c + col] = __float2half(vv);
            }
        }
    }
}

// Pool phase 1: grid-chunked over sorted nodes; per-wave run accumulation,
// one atomicAdd per (graph-run, lane) per wave.
__global__ __launch_bounds__(256) void pool_partial(const __half* __restrict__ h,
                                                    const int* __restrict__ batch, int N,
                                                    int chunk, float* __restrict__ pooled) {
    int lane = threadIdx.x & 63;
    int wv = threadIdx.x >> 6;
    int c0 = blockIdx.x * chunk;
    int c1 = min(c0 + chunk, N);
    int g_cur = -1;
    float acc = 0.f;
    for (int n = c0 + wv; n < c1; n += 4) {
        int g = batch[n];
        if (g != g_cur) {
            if (g_cur >= 0) atomicAdd(&pooled[g_cur * D + lane], acc);
            g_cur = g;
            acc = 0.f;
        }
        acc += __half2float(h[n * D + lane]);
    }
    if (g_cur >= 0) atomicAdd(&pooled[g_cur * D + lane], acc);
}

// Pool phase 2: one wave per graph, dot with lin_w.
__global__ void pool_linear(const float* __restrict__ pooled,
                            const float* __restrict__ lin_w,
                            const float* __restrict__ lin_b,
                            float* __restrict__ out, int G) {
    int lane = threadIdx.x & 63;
    int g = blockIdx.x * (blockDim.x >> 6) + (threadIdx.x >> 6);
    if (g >= G) return;
    float t = pooled[g * D + lane] * lin_w[lane];
#pragma unroll
    for (int off = 32; off >= 1; off >>= 1) t += __shfl_down(t, off, 64);
    if (lane == 0) out[g] = t + lin_b[0];
}

extern "C" void kernel_launch(void* const* d_in, const int* in_sizes, int n_in,
                              void* d_out, int out_size, void* d_ws, size_t ws_size,
                              hipStream_t stream) {
    const float* x      = (const float*)d_in[0];
    const int*   edges  = (const int*)d_in[1];
    const int*   batch  = (const int*)d_in[2];
    const float* W1     = (const float*)d_in[3];
    const float* b1     = (const float*)d_in[4];
    const float* W2     = (const float*)d_in[5];
    const float* b2     = (const float*)d_in[6];
    const float* W3     = (const float*)d_in[7];
    const float* b3     = (const float*)d_in[8];
    const float* lin_w  = (const float*)d_in[9];
    const float* lin_b  = (const float*)d_in[10];
    float* out = (float*)d_out;

    const int N = in_sizes[2];        // 100000
    const int E = in_sizes[1] / 2;    // 1600000
    const int G = out_size;           // 64 graphs
    const int nb = (N + 255) >> 8;    // 391 buckets of 256 nodes

    const int* e_src = edges;         // edge_index[0]
    const int* e_dst = edges + E;     // edge_index[1]

    // workspace layout (4B-element offsets, 64-elem aligned)
    auto al = [](long v) { return (v + 63) & ~63L; };
    long o_gcur   = 0;                       // NBMAX ints
    long o_pooled = al(o_gcur + NBMAX);      // G*D floats
    long o_gbase  = al(o_pooled + (long)G * D);
    long o_rowptr = al(o_gbase + nb + 1);
    long o_dis    = al(o_rowptr + N + 1);
    long o_adjs   = al(o_dis + N);
    long o_xh     = al(o_adjs + E);              // N*D halves
    long o_hA     = al(o_xh + (long)N * D / 2);  // aliases bpair (8MB < 25.6MB slot)
    long o_hB     = o_hA + (long)N * D;          // fp32-sized slots used as half buffers

    int*    gcursor = (int*)d_ws + o_gcur;
    float*  pooled  = (float*)d_ws + o_pooled;
    int*    gbase   = (int*)d_ws + o_gbase;
    int*    row_ptr = (int*)d_ws + o_rowptr;
    float*  dis     = (float*)d_ws + o_dis;
    int*    adj     = (int*)d_ws + o_adjs;
    __half* xh      = (__half*)((float*)d_ws + o_xh);
    __half* hA      = (__half*)((float*)d_ws + o_hA);
    __half* hB      = (__half*)((float*)d_ws + o_hB);
    // bpair (nb*BCAP uints = 8 MB) aliases hA slot: dead before layer 2 writes hA.
    unsigned* bpair = (unsigned*)hA;

    // zero gcursor + pooled (contiguous)
    int nz = (int)(o_pooled + (long)G * D);
    zero_ints<<<(nz + 255) / 256, 256, 0, stream>>>((int*)d_ws, nz);

    // CSR build first (produces dis), then pre-scaled fp16 convert of x
    bucket_scatter<<<(E + 4095) / 4096, 256, 0, stream>>>(e_src, e_dst, E, nb, gcursor, bpair);
    scan_buckets<<<1, 512, 0, stream>>>(gcursor, nb, gbase);
    bucket_build<<<nb, 256, 0, stream>>>(bpair, nb, N, gcursor, gbase, row_ptr, dis, adj);

    int n2 = N * D / 2;
    prescale_x<<<(n2 + 255) / 256, 256, 0, stream>>>(x, dis, xh, n2);

    // fused GCN layers: xh -> hB -> hA -> hB
    // layers 1,2 store dis-pre-scaled output; layer 3 stores plain relu for pooling
    const int tl_blocks = (N + TILE - 1) / TILE;
    tile_layer<<<tl_blocks, 256, 0, stream>>>(xh, row_ptr, adj, dis, W1, b1, hB, N, 1);
    tile_layer<<<tl_blocks, 256, 0, stream>>>(hB, row_ptr, adj, dis, W2, b2, hA, N, 1);
    tile_layer<<<tl_blocks, 256, 0, stream>>>(hA, row_ptr, adj, dis, W3, b3, hB, N, 0);

    // pool + final linear
    const int pool_blocks = 512;
    const int chunk = (N + pool_blocks - 1) / pool_blocks;
    pool_partial<<<pool_blocks, 256, 0, stream>>>(hB, batch, N, chunk, pooled);
    pool_linear<<<(G + 3) / 4, 256, 0, stream>>>(pooled, lin_w, lin_b, out, G);
}

// Round 11
// 377.766 us; speedup vs baseline: 1.1331x; 1.0797x over previous
//
#include <hip/hip_runtime.h>
#include <hip/hip_fp16.h>

#define D 64
#define NBMAX 512      // max buckets (nodes/256, N<=131072)
#define BCAP 5120      // per-bucket capacity
#define TILE 64        // nodes per block in tile_layer
#define AST 68         // LDS acc row stride in floats (breaks pow-2 banks, 16B-aligned)
#define ACAP 448       // per-wave LDS adjacency buffer (entries)

typedef __attribute__((ext_vector_type(8))) short short8;
typedef __attribute__((ext_vector_type(4))) float float4v;

static __device__ __forceinline__ unsigned short f2bf(float x) {
    unsigned u = __float_as_uint(x);
    u += 0x7FFFu + ((u >> 16) & 1);   // RNE
    return (unsigned short)(u >> 16);
}

__global__ void zero_ints(int* __restrict__ p, int n) {
    int i = blockIdx.x * blockDim.x + threadIdx.x;
    if (i < n) p[i] = 0;
}

// x (fp32) -> xh (fp16), pre-scaled by dis[row]: s = dis[n]*x[n]
__global__ void prescale_x(const float* __restrict__ x, const float* __restrict__ dis,
                           __half* __restrict__ out, int n2) {
    int i = blockIdx.x * blockDim.x + threadIdx.x;
    if (i < n2) {
        int n = i >> 5;                 // 32 half2 per row
        float d = dis[n];
        float2 v = ((const float2*)x)[i];
        ((__half2*)out)[i] = __floats2half2_rn(v.x * d, v.y * d);
    }
}

// Bin edges into buckets of 256 consecutive dst nodes. Entry packed to 4B:
// (src << 8) | (dst & 255)   (src < 2^24).
__global__ __launch_bounds__(256) void bucket_scatter(const int* __restrict__ src,
                                                      const int* __restrict__ dst, int E,
                                                      int nb, int* __restrict__ gcursor,
                                                      unsigned* __restrict__ bpair) {
    __shared__ int lhist[NBMAX];
    __shared__ int lbase[NBMAX];
    int t = threadIdx.x;
    for (int i = t; i < nb; i += 256) lhist[i] = 0;
    __syncthreads();
    int e0 = blockIdx.x * 4096, e1 = min(e0 + 4096, E);
    for (int e = e0 + t; e < e1; e += 256) atomicAdd(&lhist[dst[e] >> 8], 1);
    __syncthreads();
    for (int i = t; i < nb; i += 256) {
        int c = lhist[i];
        lbase[i] = c ? atomicAdd(&gcursor[i], c) : 0;
        lhist[i] = 0;
    }
    __syncthreads();
    for (int e = e0 + t; e < e1; e += 256) {
        int d = dst[e];
        int b = d >> 8;
        int r = lbase[b] + atomicAdd(&lhist[b], 1);
        if (r < BCAP)
            bpair[(long)b * BCAP + r] = ((unsigned)src[e] << 8) | (unsigned)(d & 255);
    }
}

// Exclusive scan of nb (<512) bucket counts -> gbase, total at gbase[nb].
__global__ void scan_buckets(const int* __restrict__ gcursor, int B, int* __restrict__ gbase) {
    __shared__ int s[512];
    int t = threadIdx.x;
    s[t] = (t < B) ? gcursor[t] : 0;
    __syncthreads();
    for (int off = 1; off < 512; off <<= 1) {
        int v = (t >= off) ? s[t - off] : 0;
        __syncthreads();
        s[t] += v;
        __syncthreads();
    }
    if (t < B) gbase[t] = (t == 0) ? 0 : s[t - 1];
    if (t == 0) gbase[B] = s[511];
}

// One block per bucket: local histogram + scan in LDS, emit row_ptr/dis and
// adj entries packed as (src << 6) | (dst & 63)  (tile-local dst, TILE=64).
__global__ __launch_bounds__(256) void bucket_build(const unsigned* __restrict__ bpair,
                                                    int nb, int N,
                                                    const int* __restrict__ gcursor,
                                                    const int* __restrict__ gbase,
                                                    int* __restrict__ row_ptr,
                                                    float* __restrict__ dis,
                                                    int* __restrict__ adj) {
    __shared__ int hist[256];
    __shared__ int cur[256];
    __shared__ int wsum[4];
    int b = blockIdx.x, t = threadIdx.x;
    int cnt = gcursor[b];
    if (cnt > BCAP) cnt = BCAP;
    int ebase = gbase[b];
    const unsigned* bp = bpair + (long)b * BCAP;

    hist[t] = 0;
    __syncthreads();
    for (int i = t; i < cnt; i += 256) atomicAdd(&hist[bp[i] & 255u], 1);
    __syncthreads();
    int val = hist[t];
    int lane = t & 63, wv = t >> 6;
    int v = val;
#pragma unroll
    for (int off = 1; off < 64; off <<= 1) {
        int u = __shfl_up(v, off, 64);
        if (lane >= off) v += u;
    }
    if (lane == 63) wsum[wv] = v;
    __syncthreads();
    int wo = 0;
#pragma unroll
    for (int w = 0; w < 4; w++)
        if (w < wv) wo += wsum[w];
    int excl = wo + v - val;
    int node = (b << 8) + t;
    if (node < N) {
        row_ptr[node] = ebase + excl;
        dis[node] = rsqrtf((float)(val + 1));  // +1 self-loop
    }
    cur[t] = ebase + excl;
    __syncthreads();
    for (int i = t; i < cnt; i += 256) {
        unsigned p = bp[i];
        unsigned dl = p & 255u;
        int pos = atomicAdd(&cur[dl], 1);
        adj[pos] = (int)((p >> 8) << 6) | (int)(dl & 63u);
    }
    if (b == 0 && t == 0) row_ptr[N] = gbase[nb];
}

// Tile GCN layer on pre-scaled storage s[n] = dis[n]*h[n]:
//   y[n] = dis[n] * ( sum_a s[a] + s[n] );  o = relu(y @ W + b); store (*dis if scale_out)
// Block = 64-node tile. Phase 1: each wave takes a contiguous quarter of the
// tile's CSR edge range, bulk-copies its adjacency slice into wave-private LDS,
// then sweeps 8 group-streams (lane = (group, chunk)) issuing row-gathers in
// batches of 4 (independent addresses from LDS -> 4 loads in flight; no global
// dependent chain). Run-accumulate per lane, flush to LDS fp32 acc via ds atomics
// on node change. Phase 2: per-wave MFMA (16 nodes x 64) @ W (bf16 frags).
__global__ __launch_bounds__(256) void tile_layer(const __half* __restrict__ in,
                                                  const int* __restrict__ row_ptr,
                                                  const int* __restrict__ adj,
                                                  const float* __restrict__ dis,
                                                  const float* __restrict__ Wg,
                                                  const float* __restrict__ bias,
                                                  __half* __restrict__ out,
                                                  int N, int scale_out) {
    __shared__ float acc[TILE * AST];       // 17408 B
    __shared__ int adjbuf[4][ACAP];         // 7168 B, wave-private slices

    int t = threadIdx.x;
    int lane = t & 63;
    int w = t >> 6;
    int gs = lane >> 3, cs = lane & 7;
    int col = lane & 15, quad = lane >> 4;

    int t0 = blockIdx.x * TILE;
    int nend = min(t0 + TILE, N);

    // init: acc row n = s[n] (self-loop term), zeros for padding rows
#pragma unroll
    for (int i = 0; i < 16; i++) {
        int nl = w * 16 + i;
        int n = t0 + nl;
        float v = (n < nend) ? __half2float(in[(long)n * D + lane]) : 0.f;
        acc[nl * AST + lane] = v;
    }
    __syncthreads();

    // ---- edge sweep ----
    int eb = row_ptr[t0];
    int ee = row_ptr[nend];
    int etot = ee - eb;
    int per = (etot + 3) >> 2;
    int a0 = eb + w * per;
    int b0 = min(a0 + per, ee);
    const int4* in4 = (const int4*)in;
    int* adjw = adjbuf[w];

    int cur_nl = -1;
    float racc[8];
#pragma unroll
    for (int q = 0; q < 8; q++) racc[q] = 0.f;

    for (int base = a0; base < b0; base += ACAP) {
        int clen = min(ACAP, b0 - base);
        // cooperative wave-copy of adj slice (coalesced dwords); wave-private.
        for (int i = lane; i < clen; i += 64) adjw[i] = adj[base + i];
        __builtin_amdgcn_s_waitcnt(0);   // drain lds writes + vm before reads

        int glen = (clen + 7) >> 3;
        int gst = gs * glen;
        int gend = min(gst + glen, clen);

        for (int i = gst; i < gend; i += 4) {
            int pk0, pk1, pk2, pk3;
            bool ok0, ok1, ok2, ok3;
            {
                int i0 = i, i1 = i + 1, i2 = i + 2, i3 = i + 3;
                ok0 = i0 < gend; ok1 = i1 < gend; ok2 = i2 < gend; ok3 = i3 < gend;
                int g1 = gend - 1;
                pk0 = adjw[ok0 ? i0 : g1];
                pk1 = adjw[ok1 ? i1 : g1];
                pk2 = adjw[ok2 ? i2 : g1];
                pk3 = adjw[ok3 ? i3 : g1];
            }
            // 4 independent row-gathers issued together
            int4 r0 = in4[(long)(pk0 >> 6) * 8 + cs];
            int4 r1 = in4[(long)(pk1 >> 6) * 8 + cs];
            int4 r2 = in4[(long)(pk2 >> 6) * 8 + cs];
            int4 r3 = in4[(long)(pk3 >> 6) * 8 + cs];

#define PROC(pk, rr, okf)                                                     \
            if (okf) {                                                        \
                int nl = (pk) & 63;                                           \
                if (nl != cur_nl) {                                           \
                    if (cur_nl >= 0) {                                        \
                        float* bp = &acc[cur_nl * AST + cs * 8];              \
                        _Pragma("unroll")                                     \
                        for (int q = 0; q < 8; q++) atomicAdd(bp + q, racc[q]); \
                    }                                                         \
                    _Pragma("unroll")                                         \
                    for (int q = 0; q < 8; q++) racc[q] = 0.f;                \
                    cur_nl = nl;                                              \
                }                                                             \
                float2 f0 = __half22float2(*(__half2*)&rr.x);                 \
                float2 f1 = __half22float2(*(__half2*)&rr.y);                 \
                float2 f2 = __half22float2(*(__half2*)&rr.z);                 \
                float2 f3 = __half22float2(*(__half2*)&rr.w);                 \
                racc[0] += f0.x; racc[1] += f0.y;                             \
                racc[2] += f1.x; racc[3] += f1.y;                             \
                racc[4] += f2.x; racc[5] += f2.y;                             \
                racc[6] += f3.x; racc[7] += f3.y;                             \
            }
            PROC(pk0, r0, ok0)
            PROC(pk1, r1, ok1)
            PROC(pk2, r2, ok2)
            PROC(pk3, r3, ok3)
#undef PROC
        }
    }
    if (cur_nl >= 0) {
        float* bp = &acc[cur_nl * AST + cs * 8];
#pragma unroll
        for (int q = 0; q < 8; q++) atomicAdd(bp + q, racc[q]);
    }
    __syncthreads();

    // ---- MFMA epilogue: per wave, rows w*16 .. w*16+15 ----
    // B frags (W bf16): B[k=32s+quad*8+j][d=16c+col]  (R7-verified mapping)
    short8 Bf[2][4];
#pragma unroll
    for (int s = 0; s < 2; s++)
#pragma unroll
        for (int c = 0; c < 4; c++) {
            short8 f;
#pragma unroll
            for (int j = 0; j < 8; j++)
                f[j] = (short)f2bf(Wg[(32 * s + quad * 8 + j) * D + 16 * c + col]);
            Bf[s][c] = f;
        }
    float bias_c[4];
#pragma unroll
    for (int c = 0; c < 4; c++) bias_c[c] = bias[16 * c + col];

    // A frags: row m = col, k = 32s + quad*8 + j; scale row by dis (y = dn*acc)
    int arow = w * 16 + col;
    int anode = t0 + arow;
    float dA = (anode < N) ? dis[anode] : 0.f;
    short8 Af[2];
#pragma unroll
    for (int s = 0; s < 2; s++) {
        const float* ap = &acc[arow * AST + 32 * s + quad * 8];
        float4v p0 = *(const float4v*)ap;
        float4v p1 = *(const float4v*)(ap + 4);
        short8 f;
#pragma unroll
        for (int j = 0; j < 4; j++) {
            f[j] = (short)f2bf(p0[j] * dA);
            f[4 + j] = (short)f2bf(p1[j] * dA);
        }
        Af[s] = f;
    }

    float4v accv[4];
#pragma unroll
    for (int c = 0; c < 4; c++) {
        float4v z = {0.f, 0.f, 0.f, 0.f};
        accv[c] = __builtin_amdgcn_mfma_f32_16x16x32_bf16(Af[0], Bf[0][c], z, 0, 0, 0);
        accv[c] = __builtin_amdgcn_mfma_f32_16x16x32_bf16(Af[1], Bf[1][c], accv[c], 0, 0, 0);
    }

    // C layout: col = lane&15 (dim 16c+col), row = quad*4 + r (node)
#pragma unroll
    for (int r = 0; r < 4; r++) {
        int node = t0 + w * 16 + quad * 4 + r;
        if (node < N) {
            float dn = scale_out ? dis[node] : 1.f;
#pragma unroll
            for (int c = 0; c < 4; c++) {
                float vv = fmaxf(accv[c][r] + bias_c[c], 0.f) * dn;
                out[(long)node * D + 16 * c + col] = __float2half(vv);
            }
        }
    }
}

// Pool phase 1: grid-chunked over sorted nodes; per-wave run accumulation,
// one atomicAdd per (graph-run, lane) per wave.
__global__ __launch_bounds__(256) void pool_partial(const __half* __restrict__ h,
                                                    const int* __restrict__ batch, int N,
                                                    int chunk, float* __restrict__ pooled) {
    int lane = threadIdx.x & 63;
    int wv = threadIdx.x >> 6;
    int c0 = blockIdx.x * chunk;
    int c1 = min(c0 + chunk, N);
    int g_cur = -1;
    float acc = 0.f;
    for (int n = c0 + wv; n < c1; n += 4) {
        int g = batch[n];
        if (g != g_cur) {
            if (g_cur >= 0) atomicAdd(&pooled[g_cur * D + lane], acc);
            g_cur = g;
            acc = 0.f;
        }
        acc += __half2float(h[n * D + lane]);
    }
    if (g_cur >= 0) atomicAdd(&pooled[g_cur * D + lane], acc);
}

// Pool phase 2: one wave per graph, dot with lin_w.
__global__ void pool_linear(const float* __restrict__ pooled,
                            const float* __restrict__ lin_w,
                            const float* __restrict__ lin_b,
                            float* __restrict__ out, int G) {
    int lane = threadIdx.x & 63;
    int g = blockIdx.x * (blockDim.x >> 6) + (threadIdx.x >> 6);
    if (g >= G) return;
    float t = pooled[g * D + lane] * lin_w[lane];
#pragma unroll
    for (int off = 32; off >= 1; off >>= 1) t += __shfl_down(t, off, 64);
    if (lane == 0) out[g] = t + lin_b[0];
}

extern "C" void kernel_launch(void* const* d_in, const int* in_sizes, int n_in,
                              void* d_out, int out_size, void* d_ws, size_t ws_size,
                              hipStream_t stream) {
    const float* x      = (const float*)d_in[0];
    const int*   edges  = (const int*)d_in[1];
    const int*   batch  = (const int*)d_in[2];
    const float* W1     = (const float*)d_in[3];
    const float* b1     = (const float*)d_in[4];
    const float* W2     = (const float*)d_in[5];
    const float* b2     = (const float*)d_in[6];
    const float* W3     = (const float*)d_in[7];
    const float* b3     = (const float*)d_in[8];
    const float* lin_w  = (const float*)d_in[9];
    const float* lin_b  = (const float*)d_in[10];
    float* out = (float*)d_out;

    const int N = in_sizes[2];        // 100000
    const int E = in_sizes[1] / 2;    // 1600000
    const int G = out_size;           // 64 graphs
    const int nb = (N + 255) >> 8;    // 391 buckets of 256 nodes

    const int* e_src = edges;         // edge_index[0]
    const int* e_dst = edges + E;     // edge_index[1]

    // workspace layout (4B-element offsets, 64-elem aligned)
    auto al = [](long v) { return (v + 63) & ~63L; };
    long o_gcur   = 0;                       // NBMAX ints
    long o_pooled = al(o_gcur + NBMAX);      // G*D floats
    long o_gbase  = al(o_pooled + (long)G * D);
    long o_rowptr = al(o_gbase + nb + 1);
    long o_dis    = al(o_rowptr + N + 1);
    long o_adjs   = al(o_dis + N);
    long o_xh     = al(o_adjs + E);              // N*D halves
    long o_hA     = al(o_xh + (long)N * D / 2);  // aliases bpair (8MB < 25.6MB slot)
    long o_hB     = o_hA + (long)N * D;          // fp32-sized slots used as half buffers

    int*    gcursor = (int*)d_ws + o_gcur;
    float*  pooled  = (float*)d_ws + o_pooled;
    int*    gbase   = (int*)d_ws + o_gbase;
    int*    row_ptr = (int*)d_ws + o_rowptr;
    float*  dis     = (float*)d_ws + o_dis;
    int*    adj     = (int*)d_ws + o_adjs;
    __half* xh      = (__half*)((float*)d_ws + o_xh);
    __half* hA      = (__half*)((float*)d_ws + o_hA);
    __half* hB      = (__half*)((float*)d_ws + o_hB);
    // bpair (nb*BCAP uints = 8 MB) aliases hA slot: dead before layer 2 writes hA.
    unsigned* bpair = (unsigned*)hA;

    // zero gcursor + pooled (contiguous)
    int nz = (int)(o_pooled + (long)G * D);
    zero_ints<<<(nz + 255) / 256, 256, 0, stream>>>((int*)d_ws, nz);

    // CSR build first (produces dis), then pre-scaled fp16 convert of x
    bucket_scatter<<<(E + 4095) / 4096, 256, 0, stream>>>(e_src, e_dst, E, nb, gcursor, bpair);
    scan_buckets<<<1, 512, 0, stream>>>(gcursor, nb, gbase);
    bucket_build<<<nb, 256, 0, stream>>>(bpair, nb, N, gcursor, gbase, row_ptr, dis, adj);

    int n2 = N * D / 2;
    prescale_x<<<(n2 + 255) / 256, 256, 0, stream>>>(x, dis, xh, n2);

    // fused GCN layers: xh -> hB -> hA -> hB
    // layers 1,2 store dis-pre-scaled output; layer 3 stores plain relu for pooling
    const int tl_blocks = (N + TILE - 1) / TILE;
    tile_layer<<<tl_blocks, 256, 0, stream>>>(xh, row_ptr, adj, dis, W1, b1, hB, N, 1);
    tile_layer<<<tl_blocks, 256, 0, stream>>>(hB, row_ptr, adj, dis, W2, b2, hA, N, 1);
    tile_layer<<<tl_blocks, 256, 0, stream>>>(hA, row_ptr, adj, dis, W3, b3, hB, N, 0);

    // pool + final linear
    const int pool_blocks = 512;
    const int chunk = (N + pool_blocks - 1) / pool_blocks;
    pool_partial<<<pool_blocks, 256, 0, stream>>>(hB, batch, N, chunk, pooled);
    pool_linear<<<(G + 3) / 4, 256, 0, stream>>>(pooled, lin_w, lin_b, out, G);
}